// Round 10
// baseline (209.980 us; speedup 1.0000x reference)
//
#include <hip/hip_runtime.h>
#include <math.h>

#define HW 4096

typedef __attribute__((ext_vector_type(8))) short bh8;
typedef __attribute__((ext_vector_type(4))) float f32x4;
typedef __attribute__((ext_vector_type(2))) unsigned int u32x2;
typedef unsigned int u32;
typedef unsigned short u16;

__device__ __forceinline__ u16 f2bf(float f) {
  union { float f; u32 u; } v; v.f = f;
  u32 u = v.u;
  return (u16)((u + 0x7FFFu + ((u >> 16) & 1u)) >> 16);
}
__device__ __forceinline__ float bf2f(u16 h) {
  union { u32 u; float f; } v; v.u = ((u32)h) << 16;
  return v.f;
}
__device__ __forceinline__ float ubits2f(u32 u) {
  union { u32 u; float f; } v; v.u = u;
  return v.f;
}
__device__ __forceinline__ u32 cvt_pk_bf16(float lo, float hi) {
  u32 r;
  asm("v_cvt_pk_bf16_f32 %0, %1, %2" : "=v"(r) : "v"(lo), "v"(hi));
  return r;
}
__device__ __forceinline__ float fexp2(float x) {
  float r;
  asm("v_exp_f32 %0, %1" : "=v"(r) : "v"(x));
  return r;
}

// ---------------------------------------------------------------------------
// kv projection (r11 MFMA split-precision) + M-zero prologue. (R9, frozen)
// XCD pinning: 1D grid 512, b = bid&7. block 256.
// ---------------------------------------------------------------------------
__global__ __launch_bounds__(256) void kv_proj(
    const float* __restrict__ xs,
    const float* __restrict__ w1, const float* __restrict__ b1,
    const float* __restrict__ w2, const float* __restrict__ b2,
    u32* __restrict__ Knm, u16* __restrict__ Vcm,
    u16* __restrict__ K2t, u16* __restrict__ V2t,
    const float* __restrict__ cw, const float* __restrict__ gamma,
    const float* __restrict__ beta, const float* __restrict__ mean,
    const float* __restrict__ var, u16* __restrict__ Wg,
    float* __restrict__ shb, float* __restrict__ M) {
  __shared__ __align__(16) u16 XsH[64][72];
  __shared__ __align__(16) u16 XsL[64][72];
  __shared__ u32 LtK[64][33];
  const int bid = blockIdx.x;
  const int b = bid & 7, n0 = (bid >> 3) * 64;
  const int t = threadIdx.x;
  const int wq = t >> 6, lane = t & 63, lq = lane & 15, quad = lane >> 4;
  const float* xsb = xs + (size_t)b * 128 * HW;

  // ---- fused wcvt + M zeroing ----
  {
    int gid = bid * 256 + t;  // 0..131071
    for (int i = gid; i < 147456; i += 131072) {
      int tap = i >> 14, oc = (i >> 7) & 127, ic = i & 127;
      float sc = gamma[oc] * rsqrtf(var[oc] + 1e-5f);
      Wg[i] = f2bf(cw[((size_t)(oc * 128 + ic)) * 9 + tap] * sc);
    }
    if (gid < 128) {
      float sc = gamma[gid] * rsqrtf(var[gid] + 1e-5f);
      shb[gid] = beta[gid] - mean[gid] * sc;
    }
    if (gid < 32768) M[gid] = 0.f;  // 8 * 4096
  }

  for (int br = 0; br < 2; ++br) {
    const float* W = br ? w2 : w1;
    const float* bias = br ? b2 : b1;
    const float* src = xsb + (br ? 64 * HW : 0);

    // ---- W fragments -> registers, split hi/lo bf16 ----
    bh8 wh[2][2], wl[2][2];
#pragma unroll
    for (int jt = 0; jt < 2; ++jt)
#pragma unroll
      for (int s = 0; s < 2; ++s) {
        const float* wr = W + (size_t)(wq * 32 + jt * 16 + lq) * 64 + s * 32 + quad * 8;
        float4 a0 = *(const float4*)wr;
        float4 a1 = *(const float4*)(wr + 4);
        float f[8] = {a0.x, a0.y, a0.z, a0.w, a1.x, a1.y, a1.z, a1.w};
        union { u32 u[4]; bh8 v; } H, L;
#pragma unroll
        for (int p = 0; p < 4; ++p) {
          u32 hp = cvt_pk_bf16(f[2 * p], f[2 * p + 1]);
          float h0 = ubits2f(hp << 16);
          float h1 = ubits2f(hp & 0xFFFF0000u);
          H.u[p] = hp;
          L.u[p] = cvt_pk_bf16(f[2 * p] - h0, f[2 * p + 1] - h1);
        }
        wh[jt][s] = H.v;
        wl[jt][s] = L.v;
      }

    if (br) __syncthreads();  // prior branch's LDS readers/writers done
    // ---- stage x tile transposed to LDS as hi/lo bf16 ----
    {
      const int n = t & 63, cg = t >> 6;
#pragma unroll
      for (int s8 = 0; s8 < 8; ++s8) {
        int ch0 = s8 * 8 + cg * 2;
        float f0 = src[(size_t)ch0 * HW + n0 + n];
        float f1 = src[(size_t)(ch0 + 1) * HW + n0 + n];
        u32 hp = cvt_pk_bf16(f0, f1);
        float h0 = ubits2f(hp << 16);
        float h1 = ubits2f(hp & 0xFFFF0000u);
        u32 lp = cvt_pk_bf16(f0 - h0, f1 - h1);
        *(u32*)&XsH[n][ch0] = hp;
        *(u32*)&XsL[n][ch0] = lp;
      }
    }
    __syncthreads();

    // ---- MFMA: out[j][n] = W[j][:] . x[:][n], 8 C-tiles per wave ----
    f32x4 acc[2][4];
#pragma unroll
    for (int nt = 0; nt < 4; ++nt) {
      const int xr = nt * 16 + lq;
      bh8 xh0 = *(const bh8*)&XsH[xr][quad * 8];
      bh8 xh1 = *(const bh8*)&XsH[xr][32 + quad * 8];
      bh8 xl0 = *(const bh8*)&XsL[xr][quad * 8];
      bh8 xl1 = *(const bh8*)&XsL[xr][32 + quad * 8];
#pragma unroll
      for (int jt = 0; jt < 2; ++jt) {
        f32x4 a = (f32x4)(0.f);
        a = __builtin_amdgcn_mfma_f32_16x16x32_bf16(wh[jt][0], xh0, a, 0, 0, 0);
        a = __builtin_amdgcn_mfma_f32_16x16x32_bf16(wh[jt][1], xh1, a, 0, 0, 0);
        a = __builtin_amdgcn_mfma_f32_16x16x32_bf16(wh[jt][0], xl0, a, 0, 0, 0);
        a = __builtin_amdgcn_mfma_f32_16x16x32_bf16(wh[jt][1], xl1, a, 0, 0, 0);
        a = __builtin_amdgcn_mfma_f32_16x16x32_bf16(wl[jt][0], xh0, a, 0, 0, 0);
        a = __builtin_amdgcn_mfma_f32_16x16x32_bf16(wl[jt][1], xh1, a, 0, 0, 0);
        acc[jt][nt] = a;
      }
    }

    // ---- epilogue ----
    if (br == 0) {
      if (wq < 2) {  // j 0..63 -> K1: pack pairs into LtK
#pragma unroll
        for (int jt = 0; jt < 2; ++jt) {
          float4 bv = *(const float4*)&bias[wq * 32 + jt * 16 + quad * 4];
#pragma unroll
          for (int nt = 0; nt < 4; ++nt) {
            f32x4 a = acc[jt][nt];
            LtK[nt * 16 + lq][wq * 16 + jt * 8 + quad * 2] =
                cvt_pk_bf16(a[0] + bv.x, a[1] + bv.y);
            LtK[nt * 16 + lq][wq * 16 + jt * 8 + quad * 2 + 1] =
                cvt_pk_bf16(a[2] + bv.z, a[3] + bv.w);
          }
        }
      } else {  // j 64..127 -> V1 ch-major bf16
#pragma unroll
        for (int jt = 0; jt < 2; ++jt) {
          float4 bv = *(const float4*)&bias[wq * 32 + jt * 16 + quad * 4];
          float bvv[4] = {bv.x, bv.y, bv.z, bv.w};
#pragma unroll
          for (int nt = 0; nt < 4; ++nt)
#pragma unroll
            for (int r = 0; r < 4; ++r) {
              int ch = (wq - 2) * 32 + jt * 16 + quad * 4 + r;
              Vcm[((size_t)b * 64 + ch) * HW + n0 + nt * 16 + lq] =
                  f2bf(acc[jt][nt][r] + bvv[r]);
            }
        }
      }
      __syncthreads();
      // coalesced n-major K write: rows of 32 uints (64 bf16)
#pragma unroll
      for (int p = 0; p < 8; ++p) {
        int idx = p * 256 + t;
        int n = idx >> 5, cc = idx & 31;
        Knm[((size_t)b * HW + n0 + n) * 32 + cc] = LtK[n][cc];
      }
    } else {  // branch 2: K2t / V2t ch-major bf16
      u16* base = (wq < 2) ? (K2t + (size_t)b * 64 * HW) : (V2t + (size_t)b * 64 * HW);
      const int chb = (wq & 1) * 32;
#pragma unroll
      for (int jt = 0; jt < 2; ++jt) {
        float4 bv = *(const float4*)&bias[wq * 32 + jt * 16 + quad * 4];
        float bvv[4] = {bv.x, bv.y, bv.z, bv.w};
#pragma unroll
        for (int nt = 0; nt < 4; ++nt)
#pragma unroll
          for (int r = 0; r < 4; ++r) {
            int ch = chb + jt * 16 + quad * 4 + r;
            base[(size_t)ch * HW + n0 + nt * 16 + lq] =
                f2bf(acc[jt][nt][r] + bvv[r]);
          }
      }
    }
  }
}

// ---------------------------------------------------------------------------
// Fused dispatch (R9, frozen): R6 attention core + MFMA gram with atomicAdd
// into M. XCD pinning b = bid&7. grid 768, block 256.
// ---------------------------------------------------------------------------
__device__ __forceinline__ void attn_step(
    const bh8* kf, const bh8* vf, const bh8 (&qb)[4][2], const bh8 ones,
    f32x4 (&O)[4][4], f32x4 (&Osum)[4]) {
  f32x4 S[2][4];
  __builtin_amdgcn_s_setprio(1);
#pragma unroll
  for (int mt = 0; mt < 2; ++mt)
#pragma unroll
    for (int nt = 0; nt < 4; ++nt) {
      f32x4 a = (f32x4)(0.f);
      a = __builtin_amdgcn_mfma_f32_16x16x32_bf16(kf[mt * 2 + 0], qb[nt][0], a, 0, 0, 0);
      a = __builtin_amdgcn_mfma_f32_16x16x32_bf16(kf[mt * 2 + 1], qb[nt][1], a, 0, 0, 0);
      S[mt][nt] = a;
    }
  __builtin_amdgcn_s_setprio(0);
#pragma unroll
  for (int nt = 0; nt < 4; ++nt) {
    // p = exp2(S - 12*log2e); Q prescaled by log2e (scale cancels at norm)
    const float c = 17.312340f;  // 12 * log2(e)
    float e00 = fexp2(S[0][nt][0] - c), e01 = fexp2(S[0][nt][1] - c);
    float e02 = fexp2(S[0][nt][2] - c), e03 = fexp2(S[0][nt][3] - c);
    float e10 = fexp2(S[1][nt][0] - c), e11 = fexp2(S[1][nt][1] - c);
    float e12 = fexp2(S[1][nt][2] - c), e13 = fexp2(S[1][nt][3] - c);
    u32 A = cvt_pk_bf16(e00, e01);
    u32 B = cvt_pk_bf16(e02, e03);
    u32 C = cvt_pk_bf16(e10, e11);
    u32 D = cvt_pk_bf16(e12, e13);
    u32x2 rac = __builtin_amdgcn_permlane32_swap(A, C, 0, 0);
    u32x2 rbd = __builtin_amdgcn_permlane32_swap(B, D, 0, 0);
    u32x2 r02 = __builtin_amdgcn_permlane16_swap(rac.x, rac.y, 0, 0);
    u32x2 r13 = __builtin_amdgcn_permlane16_swap(rbd.x, rbd.y, 0, 0);
    union { u32 u[4]; bh8 v; } pb;
    pb.u[0] = r02.x;
    pb.u[1] = r13.x;
    pb.u[2] = r02.y;
    pb.u[3] = r13.y;
    __builtin_amdgcn_s_setprio(1);
#pragma unroll
    for (int ct = 0; ct < 4; ++ct)
      O[ct][nt] = __builtin_amdgcn_mfma_f32_16x16x32_bf16(vf[ct], pb.v, O[ct][nt], 0, 0, 0);
    Osum[nt] = __builtin_amdgcn_mfma_f32_16x16x32_bf16(ones, pb.v, Osum[nt], 0, 0, 0);
    __builtin_amdgcn_s_setprio(0);
  }
}

#define LOADKV(KB, KF, VF)                                            \
  do {                                                                \
    const int n0_ = (KB) * 128;                                       \
    const u16* kr_ = Kb + (size_t)(n0_ + wb + lq) * 64 + quad * 8;    \
    KF[0] = *(const bh8*)(kr_);                                       \
    KF[1] = *(const bh8*)(kr_ + 32);                                  \
    KF[2] = *(const bh8*)(kr_ + 1024);                                \
    KF[3] = *(const bh8*)(kr_ + 1056);                                \
    const u16* vr_ = Vb + (size_t)lq * HW + n0_ + wb + quad * 8;      \
    VF[0] = *(const bh8*)(vr_);                                       \
    VF[1] = *(const bh8*)(vr_ + 16 * HW);                             \
    VF[2] = *(const bh8*)(vr_ + 32 * HW);                             \
    VF[3] = *(const bh8*)(vr_ + 48 * HW);                             \
  } while (0)

__global__ __launch_bounds__(256, 2) void attn_gram(
    const float* __restrict__ xu, const float* __restrict__ xs,
    const u16* __restrict__ Knm, const u16* __restrict__ Vcm,
    u16* __restrict__ xcat,
    const u16* __restrict__ K2t, float* __restrict__ M) {
  __shared__ __align__(16) u16 SMEM[18432];  // 36864 B
  const int bid = blockIdx.x;
  const int b = bid & 7;
  const int x = bid >> 3;  // 0..95
  const int t = threadIdx.x;
  const int wq = t >> 6, lane = t & 63, lq = lane & 15, quad = lane >> 4;

  if (x >= 64) {
    // ---------------- chan_gram: split-precision MFMA + atomics ----------
    const int chunk = x - 64;   // 0..31, n-range chunk*128
    const int nn = chunk * 128;
    const float* ub = xu + ((size_t)b * 128 + 64) * HW;
    const u16* kb2 = K2t + (size_t)b * 64 * HW;
    f32x4 acc[4];
#pragma unroll
    for (int ct = 0; ct < 4; ++ct) acc[ct] = (f32x4)(0.f);
#pragma unroll
    for (int kc = 0; kc < 4; ++kc) {
      const int nb2 = nn + kc * 32 + quad * 8;
      bh8 kb_ = *(const bh8*)&kb2[(size_t)(wq * 16 + lq) * HW + nb2];
#pragma unroll
      for (int ct = 0; ct < 4; ++ct) {
        const float* ar = ub + (size_t)(ct * 16 + lq) * HW + nb2;
        float4 a0 = *(const float4*)ar;
        float4 a1 = *(const float4*)(ar + 4);
        float f[8] = {a0.x, a0.y, a0.z, a0.w, a1.x, a1.y, a1.z, a1.w};
        union { u32 u[4]; bh8 v; } H, L;
#pragma unroll
        for (int p = 0; p < 4; ++p) {
          u32 hp = cvt_pk_bf16(f[2 * p], f[2 * p + 1]);
          float h0 = ubits2f(hp << 16);
          float h1 = ubits2f(hp & 0xFFFF0000u);
          H.u[p] = hp;
          L.u[p] = cvt_pk_bf16(f[2 * p] - h0, f[2 * p + 1] - h1);
        }
        acc[ct] = __builtin_amdgcn_mfma_f32_16x16x32_bf16(H.v, kb_, acc[ct], 0, 0, 0);
        acc[ct] = __builtin_amdgcn_mfma_f32_16x16x32_bf16(L.v, kb_, acc[ct], 0, 0, 0);
      }
    }
    float* Mb = M + (size_t)b * 4096;
#pragma unroll
    for (int ct = 0; ct < 4; ++ct)
#pragma unroll
      for (int r = 0; r < 4; ++r)
        atomicAdd(&Mb[(ct * 16 + quad * 4 + r) * 64 + wq * 16 + lq], acc[ct][r]);
    return;
  }

  // ---------------- attention path (exact R6) ----------------
  const int q0 = x * 64;
  const int wb = wq * 32;
  const float* xub = xu + (size_t)b * 128 * HW;
  const float* xsb = xs + (size_t)b * 128 * HW;
  const u16* Kb = Knm + (size_t)b * HW * 64;
  const u16* Vb = Vcm + (size_t)b * 64 * HW;

  bh8 qb[4][2];
#pragma unroll
  for (int nt = 0; nt < 4; ++nt)
#pragma unroll
    for (int s = 0; s < 2; ++s)
#pragma unroll
      for (int j = 0; j < 8; ++j) {
        int ch = s * 32 + quad * 8 + j;
        qb[nt][s][j] =
            (short)f2bf(xub[(size_t)ch * HW + q0 + nt * 16 + lq] * 1.44269504f);
      }
  bh8 ones;
#pragma unroll
  for (int j = 0; j < 8; ++j) ones[j] = (short)0x3F80;

  f32x4 O[4][4];
#pragma unroll
  for (int ct = 0; ct < 4; ++ct)
#pragma unroll
    for (int nt = 0; nt < 4; ++nt) O[ct][nt] = (f32x4)(0.f);
  f32x4 Osum[4];
#pragma unroll
  for (int nt = 0; nt < 4; ++nt) Osum[nt] = (f32x4)(0.f);

  bh8 kfa[4], vfa[4], kfb[4], vfb[4];
  LOADKV(0, kfa, vfa);
  for (int kb = 0; kb < 32; kb += 2) {
    LOADKV(kb + 1, kfb, vfb);
    attn_step(kfa, vfa, qb, ones, O, Osum);
    if (kb + 2 < 32) LOADKV(kb + 2, kfa, vfa);
    attn_step(kfb, vfb, qb, ones, O, Osum);
  }

  // ---- epilogue: cross-wave reduce, normalize, shortcut, bf16 store ----
  float* Posc = (float*)SMEM;            // [4 waves][32 ch][68 q] = 34816 B
  float* Lred = (float*)(SMEM + 17408);  // 1024 B
  if (quad == 0) {
#pragma unroll
    for (int nt = 0; nt < 4; ++nt) Lred[(wq * 4 + nt) * 16 + lq] = Osum[nt][0];
  }

  const int q = t & 63, cg = t >> 6;
#pragma unroll
  for (int rh = 0; rh < 2; ++rh) {
    if (rh) __syncthreads();
#pragma unroll
    for (int c2 = 0; c2 < 2; ++c2)
#pragma unroll
      for (int nt = 0; nt < 4; ++nt)
#pragma unroll
        for (int r = 0; r < 4; ++r)
          Posc[(wq * 32 + c2 * 16 + quad * 4 + r) * 68 + nt * 16 + lq] =
              O[rh * 2 + c2][nt][r];
    __syncthreads();
    float li = 0.f;
#pragma unroll
    for (int w2 = 0; w2 < 4; ++w2) li += Lred[w2 * 64 + q];
    float inv = 1.f / li;
    u16 h[8];
#pragma unroll
    for (int i = 0; i < 8; ++i) {
      int chl = cg * 8 + i;
      float s = 0.f;
#pragma unroll
      for (int w2 = 0; w2 < 4; ++w2) s += Posc[(w2 * 32 + chl) * 68 + q];
      int ch = rh * 32 + chl;
      size_t g = (size_t)ch * HW + q0 + q;
      h[i] = f2bf(s * inv + xub[g] + xsb[g]);
    }
    u32 pk[4];
#pragma unroll
    for (int j = 0; j < 4; ++j) pk[j] = (u32)h[2 * j] | ((u32)h[2 * j + 1] << 16);
    u16* ob = xcat + ((size_t)b * HW + q0 + q) * 128 + rh * 32 + cg * 8;
    *(uint4*)ob = make_uint4(pk[0], pk[1], pk[2], pk[3]);
  }
}

// ---------------------------------------------------------------------------
// conv_mfma r16: chan_apply FUSED IN. The chan-half of the staged In tile is
// computed in-block (softmax(M[b]) once + V2*A + shortcut2 per staged row)
// instead of round-tripping through xcat — deletes the chan_apply kernel,
// its launch boundary, and 8.4 MB of xcat chan-half write+read. Value path
// identical to the old one (V2t bf16 -> f32, A from f32 M, f32 accum, f2bf).
// LDS 162.2 KB (<=160 KiB cap), 1 block/CU as before. XCD pinning b=bid&7.
// grid 256, block 512.
// ---------------------------------------------------------------------------
__global__ __launch_bounds__(512) void conv_mfma(
    const u16* __restrict__ X, const u16* __restrict__ Wg,
    const float* __restrict__ shb, float* __restrict__ out,
    const u16* __restrict__ V2t, const float* __restrict__ M,
    const float* __restrict__ xu, const float* __restrict__ xs) {
  __shared__ __align__(16) u16 In[4 * 66 * 136];   // 71808 B
  __shared__ __align__(16) u16 Wt[2][128 * 136];   // 69632 B
  __shared__ float As[64 * 65];                    // 16640 B
  __shared__ float red1[8][64], red2[8][64];       // 4096 B
  const int bid = blockIdx.x;
  const int b = bid & 7, h0 = (bid >> 3) * 2;
  const int t = threadIdx.x;
  const int wq = t >> 6, lane = t & 63, lq = lane & 15, quad = lane >> 4;
  const int nb = (wq & 1) * 64;
  const int mb = (wq >> 1) * 2;
  const u16* Xb = X + (size_t)b * HW * 128;

  // zero w-halo cells (iw = 0 and 65 for each ih), full 128-ch rows
  if (t < 128) {
    int ih = t >> 5, iwsel = (t >> 4) & 1, ck = t & 15;
    int iw = iwsel ? 65 : 0;
    *(uint4*)&In[(ih * 66 + iw) * 136 + ck * 8] = make_uint4(0, 0, 0, 0);
  }
  // stage input rows, ATTENTION HALF ONLY (ck<8 = ch 0..63) from xcat
  for (int ih = 0; ih < 4; ++ih) {
    int hcur = h0 - 1 + ih;
    bool ok = (hcur >= 0 && hcur < 64);
    const u16* src = Xb + (size_t)hcur * 64 * 128;
    int row = t >> 3, ck = t & 7;  // 512 thr = 64 rows x 8 ck
    uint4 d = make_uint4(0, 0, 0, 0);
    if (ok) d = *(const uint4*)(src + (size_t)row * 128 + ck * 8);
    *(uint4*)&In[(ih * 66 + 1 + row) * 136 + ck * 8] = d;
  }
  // load M[b] -> As (pitch 65)
  for (int idx = t; idx < 4096; idx += 512)
    As[(idx >> 6) * 65 + (idx & 63)] = M[(size_t)b * 4096 + idx];
  // stage tap-0 weights into buffer 0
  {
    const u16* src = Wg;
#pragma unroll
    for (int p = 0; p < 4; ++p) {
      int idx = p * 512 + t;
      int oc = idx >> 4, ck = idx & 15;
      uint4 d = *(const uint4*)(src + oc * 128 + ck * 8);
      *(uint4*)&Wt[0][oc * 136 + ck * 8] = d;
    }
  }
  __syncthreads();  // As / In-attn / Wt0 visible

  // ---- softmax over c (per column d) of As ----
  const int dcol = t & 63, dg8 = t >> 6;  // 8 groups x 8 c each
  {
    float mx = -1e30f;
#pragma unroll
    for (int i = 0; i < 8; ++i) mx = fmaxf(mx, As[(dg8 * 8 + i) * 65 + dcol]);
    red1[dg8][dcol] = mx;
  }
  __syncthreads();
  {
    float mx = red1[0][dcol];
#pragma unroll
    for (int g = 1; g < 8; ++g) mx = fmaxf(mx, red1[g][dcol]);
    float se = 0.f;
#pragma unroll
    for (int i = 0; i < 8; ++i) {
      float e = __expf(As[(dg8 * 8 + i) * 65 + dcol] - mx);
      As[(dg8 * 8 + i) * 65 + dcol] = e;  // own cells only
      se += e;
    }
    red2[dg8][dcol] = se;
  }
  __syncthreads();

  // ---- chan-half of In: cout = V2*A/sm + xu + xs (or 0 for halo rows) ----
  {
    const u16* V2b = V2t + (size_t)b * 64 * HW;
    const float* xub2 = xu + ((size_t)b * 128 + 64) * HW;
    const float* xsb2 = xs + ((size_t)b * 128 + 64) * HW;
    const int w = t & 63, dgc = t >> 6;  // 8 d per thread
    float sminv[8];
#pragma unroll
    for (int j = 0; j < 8; ++j) {
      int d = dgc * 8 + j;
      float sm = 0.f;
#pragma unroll
      for (int g = 0; g < 8; ++g) sm += red2[g][d];
      sminv[j] = 1.f / sm;
    }
    for (int ih = 0; ih < 4; ++ih) {
      int hcur = h0 - 1 + ih;
      u32 pk[4] = {0u, 0u, 0u, 0u};
      if (hcur >= 0 && hcur < 64) {
        int nsp = hcur * 64 + w;
        float acc[8];
#pragma unroll
        for (int j = 0; j < 8; ++j) acc[j] = 0.f;
        for (int c = 0; c < 64; ++c) {
          float v = bf2f(V2b[(size_t)c * HW + nsp]);
#pragma unroll
          for (int j = 0; j < 8; ++j)
            acc[j] = fmaf(v, As[c * 65 + dgc * 8 + j], acc[j]);
        }
        u16 hv[8];
#pragma unroll
        for (int j = 0; j < 8; ++j) {
          int d = dgc * 8 + j;
          hv[j] = f2bf(acc[j] * sminv[j] + xub2[(size_t)d * HW + nsp] +
                       xsb2[(size_t)d * HW + nsp]);
        }
#pragma unroll
        for (int j = 0; j < 4; ++j)
          pk[j] = (u32)hv[2 * j] | ((u32)hv[2 * j + 1] << 16);
      }
      *(uint4*)&In[(ih * 66 + 1 + w) * 136 + 64 + dgc * 8] =
          make_uint4(pk[0], pk[1], pk[2], pk[3]);
    }
  }
  __syncthreads();  // In fully ready (both halves)

  f32x4 acc[2][4];
#pragma unroll
  for (int mt = 0; mt < 2; ++mt)
#pragma unroll
    for (int nt = 0; nt < 4; ++nt) acc[mt][nt] = (f32x4)(0.f);

  for (int tap = 0; tap < 9; ++tap) {
    const int cur = tap & 1;
    if (tap < 8) {  // prefetch next tap into the other buffer
      const u16* src = Wg + (size_t)(tap + 1) * 128 * 128;
#pragma unroll
      for (int p = 0; p < 4; ++p) {
        int idx = p * 512 + t;
        int oc = idx >> 4, ck = idx & 15;
        uint4 d = *(const uint4*)(src + oc * 128 + ck * 8);
        *(uint4*)&Wt[cur ^ 1][oc * 136 + ck * 8] = d;
      }
    }
    const int dh = tap / 3, dw = tap - 3 * dh;
    const u16* Wc = &Wt[cur][0];
#pragma unroll
    for (int c = 0; c < 4; ++c) {
      bh8 bf[4];
#pragma unroll
      for (int nt = 0; nt < 4; ++nt)
        bf[nt] = *(const bh8*)&Wc[(nb + nt * 16 + lq) * 136 + c * 32 + quad * 8];
#pragma unroll
      for (int mt = 0; mt < 2; ++mt) {
        int s = (mb + mt) * 16 + lq;
        int ih = (s >> 6) + dh, iw = (s & 63) + dw;
        bh8 af = *(const bh8*)&In[(ih * 66 + iw) * 136 + c * 32 + quad * 8];
#pragma unroll
        for (int nt = 0; nt < 4; ++nt)
          acc[mt][nt] = __builtin_amdgcn_mfma_f32_16x16x32_bf16(af, bf[nt], acc[mt][nt], 0, 0, 0);
      }
    }
    __syncthreads();
  }

  float shv[4];
#pragma unroll
  for (int nt = 0; nt < 4; ++nt) shv[nt] = shb[nb + nt * 16 + lq];
#pragma unroll
  for (int mt = 0; mt < 2; ++mt) {
    int mtile = mb + mt;
    int h = h0 + (mtile >> 2);
    int w0 = ((mtile & 3) * 16) + quad * 4;
#pragma unroll
    for (int nt = 0; nt < 4; ++nt) {
      int oc = nb + nt * 16 + lq;
      float4 v;
      v.x = fmaxf(acc[mt][nt][0] + shv[nt], 0.f);
      v.y = fmaxf(acc[mt][nt][1] + shv[nt], 0.f);
      v.z = fmaxf(acc[mt][nt][2] + shv[nt], 0.f);
      v.w = fmaxf(acc[mt][nt][3] + shv[nt], 0.f);
      *(float4*)&out[((size_t)b * 128 + oc) * HW + h * 64 + w0] = v;
    }
  }
}

// ---------------------------------------------------------------------------
extern "C" void kernel_launch(void* const* d_in, const int* in_sizes, int n_in,
                              void* d_out, int out_size, void* d_ws, size_t ws_size,
                              hipStream_t stream) {
  const float* x_up   = (const float*)d_in[0];
  const float* x_skip = (const float*)d_in[1];
  const float* kv1_w  = (const float*)d_in[2];
  const float* kv1_b  = (const float*)d_in[3];
  const float* kv2_w  = (const float*)d_in[4];
  const float* kv2_b  = (const float*)d_in[5];
  const float* conv_w = (const float*)d_in[6];
  const float* bn_g   = (const float*)d_in[7];
  const float* bn_b   = (const float*)d_in[8];
  const float* bn_m   = (const float*)d_in[9];
  const float* bn_v   = (const float*)d_in[10];
  float* out = (float*)d_out;

  char* ws = (char*)d_ws;
  const size_t XCATB_B = (size_t)8 * HW * 128 * 2;  // 8.39 MB bf16 n-major
  const size_t KV16_B  = (size_t)8 * 64 * HW * 2;   // 4.19 MB
  size_t off = 0;
  u16*   xcat = (u16*)(ws + off);   off += XCATB_B;
  u16*   K2t  = (u16*)(ws + off);   off += KV16_B;
  u16*   V2t  = (u16*)(ws + off);   off += KV16_B;
  u32*   Knm  = (u32*)(ws + off);   off += KV16_B;
  u16*   Vcm  = (u16*)(ws + off);   off += KV16_B;
  float* M    = (float*)(ws + off); off += (size_t)8 * 4096 * 4;
  u16*   Wg   = (u16*)(ws + off);   off += (size_t)9 * 128 * 128 * 2;
  float* shb  = (float*)(ws + off); off += 512;
  // total ~26 MB

  kv_proj<<<512, 256, 0, stream>>>(x_skip, kv1_w, kv1_b, kv2_w, kv2_b,
                                   Knm, Vcm, K2t, V2t,
                                   conv_w, bn_g, bn_b, bn_m, bn_v, Wg,
                                   shb, M);
  attn_gram<<<768, 256, 0, stream>>>(x_up, x_skip, (const u16*)Knm, Vcm,
                                     xcat, K2t, M);
  conv_mfma<<<256, 512, 0, stream>>>(xcat, Wg, shb, out, V2t, M, x_up, x_skip);
}

// Round 11
// 205.820 us; speedup vs baseline: 1.0202x; 1.0202x over previous
//
#include <hip/hip_runtime.h>
#include <math.h>

#define HW 4096

typedef __attribute__((ext_vector_type(8))) short bh8;
typedef __attribute__((ext_vector_type(4))) float f32x4;
typedef __attribute__((ext_vector_type(2))) unsigned int u32x2;
typedef unsigned int u32;
typedef unsigned short u16;

__device__ __forceinline__ u16 f2bf(float f) {
  union { float f; u32 u; } v; v.f = f;
  u32 u = v.u;
  return (u16)((u + 0x7FFFu + ((u >> 16) & 1u)) >> 16);
}
__device__ __forceinline__ float bf2f(u16 h) {
  union { u32 u; float f; } v; v.u = ((u32)h) << 16;
  return v.f;
}
__device__ __forceinline__ float ubits2f(u32 u) {
  union { u32 u; float f; } v; v.u = u;
  return v.f;
}
__device__ __forceinline__ u32 cvt_pk_bf16(float lo, float hi) {
  u32 r;
  asm("v_cvt_pk_bf16_f32 %0, %1, %2" : "=v"(r) : "v"(lo), "v"(hi));
  return r;
}
__device__ __forceinline__ float fexp2(float x) {
  float r;
  asm("v_exp_f32 %0, %1" : "=v"(r) : "v"(x));
  return r;
}

// ---------------------------------------------------------------------------
// kv projection (r11 MFMA split-precision) + M-zero prologue.
// XCD pinning: 1D grid 512, b = bid&7 so batch b's blocks (and its K/V
// outputs in L2) live on XCD b — consumed there by attn_gram. block 256.
// ---------------------------------------------------------------------------
__global__ __launch_bounds__(256) void kv_proj(
    const float* __restrict__ xs,
    const float* __restrict__ w1, const float* __restrict__ b1,
    const float* __restrict__ w2, const float* __restrict__ b2,
    u32* __restrict__ Knm, u16* __restrict__ Vcm,
    u16* __restrict__ K2t, u16* __restrict__ V2t,
    const float* __restrict__ cw, const float* __restrict__ gamma,
    const float* __restrict__ beta, const float* __restrict__ mean,
    const float* __restrict__ var, u16* __restrict__ Wg,
    float* __restrict__ shb, float* __restrict__ M) {
  __shared__ __align__(16) u16 XsH[64][72];
  __shared__ __align__(16) u16 XsL[64][72];
  __shared__ u32 LtK[64][33];
  const int bid = blockIdx.x;
  const int b = bid & 7, n0 = (bid >> 3) * 64;
  const int t = threadIdx.x;
  const int wq = t >> 6, lane = t & 63, lq = lane & 15, quad = lane >> 4;
  const float* xsb = xs + (size_t)b * 128 * HW;

  // ---- fused wcvt + M zeroing ----
  {
    int gid = bid * 256 + t;  // 0..131071
    for (int i = gid; i < 147456; i += 131072) {
      int tap = i >> 14, oc = (i >> 7) & 127, ic = i & 127;
      float sc = gamma[oc] * rsqrtf(var[oc] + 1e-5f);
      Wg[i] = f2bf(cw[((size_t)(oc * 128 + ic)) * 9 + tap] * sc);
    }
    if (gid < 128) {
      float sc = gamma[gid] * rsqrtf(var[gid] + 1e-5f);
      shb[gid] = beta[gid] - mean[gid] * sc;
    }
    if (gid < 32768) M[gid] = 0.f;  // 8 * 4096
  }

  for (int br = 0; br < 2; ++br) {
    const float* W = br ? w2 : w1;
    const float* bias = br ? b2 : b1;
    const float* src = xsb + (br ? 64 * HW : 0);

    // ---- W fragments -> registers, split hi/lo bf16 ----
    bh8 wh[2][2], wl[2][2];
#pragma unroll
    for (int jt = 0; jt < 2; ++jt)
#pragma unroll
      for (int s = 0; s < 2; ++s) {
        const float* wr = W + (size_t)(wq * 32 + jt * 16 + lq) * 64 + s * 32 + quad * 8;
        float4 a0 = *(const float4*)wr;
        float4 a1 = *(const float4*)(wr + 4);
        float f[8] = {a0.x, a0.y, a0.z, a0.w, a1.x, a1.y, a1.z, a1.w};
        union { u32 u[4]; bh8 v; } H, L;
#pragma unroll
        for (int p = 0; p < 4; ++p) {
          u32 hp = cvt_pk_bf16(f[2 * p], f[2 * p + 1]);
          float h0 = ubits2f(hp << 16);
          float h1 = ubits2f(hp & 0xFFFF0000u);
          H.u[p] = hp;
          L.u[p] = cvt_pk_bf16(f[2 * p] - h0, f[2 * p + 1] - h1);
        }
        wh[jt][s] = H.v;
        wl[jt][s] = L.v;
      }

    if (br) __syncthreads();  // prior branch's LDS readers/writers done
    // ---- stage x tile transposed to LDS as hi/lo bf16 ----
    {
      const int n = t & 63, cg = t >> 6;
#pragma unroll
      for (int s8 = 0; s8 < 8; ++s8) {
        int ch0 = s8 * 8 + cg * 2;
        float f0 = src[(size_t)ch0 * HW + n0 + n];
        float f1 = src[(size_t)(ch0 + 1) * HW + n0 + n];
        u32 hp = cvt_pk_bf16(f0, f1);
        float h0 = ubits2f(hp << 16);
        float h1 = ubits2f(hp & 0xFFFF0000u);
        u32 lp = cvt_pk_bf16(f0 - h0, f1 - h1);
        *(u32*)&XsH[n][ch0] = hp;
        *(u32*)&XsL[n][ch0] = lp;
      }
    }
    __syncthreads();

    // ---- MFMA: out[j][n] = W[j][:] . x[:][n], 8 C-tiles per wave ----
    f32x4 acc[2][4];
#pragma unroll
    for (int nt = 0; nt < 4; ++nt) {
      const int xr = nt * 16 + lq;
      bh8 xh0 = *(const bh8*)&XsH[xr][quad * 8];
      bh8 xh1 = *(const bh8*)&XsH[xr][32 + quad * 8];
      bh8 xl0 = *(const bh8*)&XsL[xr][quad * 8];
      bh8 xl1 = *(const bh8*)&XsL[xr][32 + quad * 8];
#pragma unroll
      for (int jt = 0; jt < 2; ++jt) {
        f32x4 a = (f32x4)(0.f);
        a = __builtin_amdgcn_mfma_f32_16x16x32_bf16(wh[jt][0], xh0, a, 0, 0, 0);
        a = __builtin_amdgcn_mfma_f32_16x16x32_bf16(wh[jt][1], xh1, a, 0, 0, 0);
        a = __builtin_amdgcn_mfma_f32_16x16x32_bf16(wh[jt][0], xl0, a, 0, 0, 0);
        a = __builtin_amdgcn_mfma_f32_16x16x32_bf16(wh[jt][1], xl1, a, 0, 0, 0);
        a = __builtin_amdgcn_mfma_f32_16x16x32_bf16(wl[jt][0], xh0, a, 0, 0, 0);
        a = __builtin_amdgcn_mfma_f32_16x16x32_bf16(wl[jt][1], xh1, a, 0, 0, 0);
        acc[jt][nt] = a;
      }
    }

    // ---- epilogue ----
    if (br == 0) {
      if (wq < 2) {  // j 0..63 -> K1: pack pairs into LtK
#pragma unroll
        for (int jt = 0; jt < 2; ++jt) {
          float4 bv = *(const float4*)&bias[wq * 32 + jt * 16 + quad * 4];
#pragma unroll
          for (int nt = 0; nt < 4; ++nt) {
            f32x4 a = acc[jt][nt];
            LtK[nt * 16 + lq][wq * 16 + jt * 8 + quad * 2] =
                cvt_pk_bf16(a[0] + bv.x, a[1] + bv.y);
            LtK[nt * 16 + lq][wq * 16 + jt * 8 + quad * 2 + 1] =
                cvt_pk_bf16(a[2] + bv.z, a[3] + bv.w);
          }
        }
      } else {  // j 64..127 -> V1 ch-major bf16
#pragma unroll
        for (int jt = 0; jt < 2; ++jt) {
          float4 bv = *(const float4*)&bias[wq * 32 + jt * 16 + quad * 4];
          float bvv[4] = {bv.x, bv.y, bv.z, bv.w};
#pragma unroll
          for (int nt = 0; nt < 4; ++nt)
#pragma unroll
            for (int r = 0; r < 4; ++r) {
              int ch = (wq - 2) * 32 + jt * 16 + quad * 4 + r;
              Vcm[((size_t)b * 64 + ch) * HW + n0 + nt * 16 + lq] =
                  f2bf(acc[jt][nt][r] + bvv[r]);
            }
        }
      }
      __syncthreads();
      // coalesced n-major K write: rows of 32 uints (64 bf16)
#pragma unroll
      for (int p = 0; p < 8; ++p) {
        int idx = p * 256 + t;
        int n = idx >> 5, cc = idx & 31;
        Knm[((size_t)b * HW + n0 + n) * 32 + cc] = LtK[n][cc];
      }
    } else {  // branch 2: K2t / V2t ch-major bf16
      u16* base = (wq < 2) ? (K2t + (size_t)b * 64 * HW) : (V2t + (size_t)b * 64 * HW);
      const int chb = (wq & 1) * 32;
#pragma unroll
      for (int jt = 0; jt < 2; ++jt) {
        float4 bv = *(const float4*)&bias[wq * 32 + jt * 16 + quad * 4];
        float bvv[4] = {bv.x, bv.y, bv.z, bv.w};
#pragma unroll
        for (int nt = 0; nt < 4; ++nt)
#pragma unroll
          for (int r = 0; r < 4; ++r) {
            int ch = chb + jt * 16 + quad * 4 + r;
            base[(size_t)ch * HW + n0 + nt * 16 + lq] =
                f2bf(acc[jt][nt][r] + bvv[r]);
          }
      }
    }
  }
}

// ---------------------------------------------------------------------------
// Fused dispatch: EXACT R6 attention core (measured best, VGPR 112) + R8's
// MFMA gram with atomicAdd into M. XCD pinning: 1D grid 768, b = bid&7 —
// batch b's K/V (written by kv_proj on XCD b) are L2-resident here, and
// xcat[b] stays on XCD b for chan_apply/conv. block 256.
// ---------------------------------------------------------------------------
__device__ __forceinline__ void attn_step(
    const bh8* kf, const bh8* vf, const bh8 (&qb)[4][2], const bh8 ones,
    f32x4 (&O)[4][4], f32x4 (&Osum)[4]) {
  f32x4 S[2][4];
  __builtin_amdgcn_s_setprio(1);
#pragma unroll
  for (int mt = 0; mt < 2; ++mt)
#pragma unroll
    for (int nt = 0; nt < 4; ++nt) {
      f32x4 a = (f32x4)(0.f);
      a = __builtin_amdgcn_mfma_f32_16x16x32_bf16(kf[mt * 2 + 0], qb[nt][0], a, 0, 0, 0);
      a = __builtin_amdgcn_mfma_f32_16x16x32_bf16(kf[mt * 2 + 1], qb[nt][1], a, 0, 0, 0);
      S[mt][nt] = a;
    }
  __builtin_amdgcn_s_setprio(0);
#pragma unroll
  for (int nt = 0; nt < 4; ++nt) {
    // p = exp2(S - 12*log2e); Q prescaled by log2e (scale cancels at norm)
    const float c = 17.312340f;  // 12 * log2(e)
    float e00 = fexp2(S[0][nt][0] - c), e01 = fexp2(S[0][nt][1] - c);
    float e02 = fexp2(S[0][nt][2] - c), e03 = fexp2(S[0][nt][3] - c);
    float e10 = fexp2(S[1][nt][0] - c), e11 = fexp2(S[1][nt][1] - c);
    float e12 = fexp2(S[1][nt][2] - c), e13 = fexp2(S[1][nt][3] - c);
    u32 A = cvt_pk_bf16(e00, e01);
    u32 B = cvt_pk_bf16(e02, e03);
    u32 C = cvt_pk_bf16(e10, e11);
    u32 D = cvt_pk_bf16(e12, e13);
    u32x2 rac = __builtin_amdgcn_permlane32_swap(A, C, 0, 0);
    u32x2 rbd = __builtin_amdgcn_permlane32_swap(B, D, 0, 0);
    u32x2 r02 = __builtin_amdgcn_permlane16_swap(rac.x, rac.y, 0, 0);
    u32x2 r13 = __builtin_amdgcn_permlane16_swap(rbd.x, rbd.y, 0, 0);
    union { u32 u[4]; bh8 v; } pb;
    pb.u[0] = r02.x;
    pb.u[1] = r13.x;
    pb.u[2] = r02.y;
    pb.u[3] = r13.y;
    __builtin_amdgcn_s_setprio(1);
#pragma unroll
    for (int ct = 0; ct < 4; ++ct)
      O[ct][nt] = __builtin_amdgcn_mfma_f32_16x16x32_bf16(vf[ct], pb.v, O[ct][nt], 0, 0, 0);
    Osum[nt] = __builtin_amdgcn_mfma_f32_16x16x32_bf16(ones, pb.v, Osum[nt], 0, 0, 0);
    __builtin_amdgcn_s_setprio(0);
  }
}

#define LOADKV(KB, KF, VF)                                            \
  do {                                                                \
    const int n0_ = (KB) * 128;                                       \
    const u16* kr_ = Kb + (size_t)(n0_ + wb + lq) * 64 + quad * 8;    \
    KF[0] = *(const bh8*)(kr_);                                       \
    KF[1] = *(const bh8*)(kr_ + 32);                                  \
    KF[2] = *(const bh8*)(kr_ + 1024);                                \
    KF[3] = *(const bh8*)(kr_ + 1056);                                \
    const u16* vr_ = Vb + (size_t)lq * HW + n0_ + wb + quad * 8;      \
    VF[0] = *(const bh8*)(vr_);                                       \
    VF[1] = *(const bh8*)(vr_ + 16 * HW);                             \
    VF[2] = *(const bh8*)(vr_ + 32 * HW);                             \
    VF[3] = *(const bh8*)(vr_ + 48 * HW);                             \
  } while (0)

__global__ __launch_bounds__(256, 2) void attn_gram(
    const float* __restrict__ xu, const float* __restrict__ xs,
    const u16* __restrict__ Knm, const u16* __restrict__ Vcm,
    u16* __restrict__ xcat,
    const u16* __restrict__ K2t, float* __restrict__ M) {
  __shared__ __align__(16) u16 SMEM[18432];  // 36864 B
  const int bid = blockIdx.x;
  const int b = bid & 7;
  const int x = bid >> 3;  // 0..95
  const int t = threadIdx.x;
  const int wq = t >> 6, lane = t & 63, lq = lane & 15, quad = lane >> 4;

  if (x >= 64) {
    // ---------------- chan_gram: split-precision MFMA + atomics ----------
    const int chunk = x - 64;   // 0..31, n-range chunk*128
    const int nn = chunk * 128;
    const float* ub = xu + ((size_t)b * 128 + 64) * HW;
    const u16* kb2 = K2t + (size_t)b * 64 * HW;
    f32x4 acc[4];
#pragma unroll
    for (int ct = 0; ct < 4; ++ct) acc[ct] = (f32x4)(0.f);
#pragma unroll
    for (int kc = 0; kc < 4; ++kc) {
      const int nb2 = nn + kc * 32 + quad * 8;
      bh8 kb_ = *(const bh8*)&kb2[(size_t)(wq * 16 + lq) * HW + nb2];
#pragma unroll
      for (int ct = 0; ct < 4; ++ct) {
        const float* ar = ub + (size_t)(ct * 16 + lq) * HW + nb2;
        float4 a0 = *(const float4*)ar;
        float4 a1 = *(const float4*)(ar + 4);
        float f[8] = {a0.x, a0.y, a0.z, a0.w, a1.x, a1.y, a1.z, a1.w};
        union { u32 u[4]; bh8 v; } H, L;
#pragma unroll
        for (int p = 0; p < 4; ++p) {
          u32 hp = cvt_pk_bf16(f[2 * p], f[2 * p + 1]);
          float h0 = ubits2f(hp << 16);
          float h1 = ubits2f(hp & 0xFFFF0000u);
          H.u[p] = hp;
          L.u[p] = cvt_pk_bf16(f[2 * p] - h0, f[2 * p + 1] - h1);
        }
        acc[ct] = __builtin_amdgcn_mfma_f32_16x16x32_bf16(H.v, kb_, acc[ct], 0, 0, 0);
        acc[ct] = __builtin_amdgcn_mfma_f32_16x16x32_bf16(L.v, kb_, acc[ct], 0, 0, 0);
      }
    }
    float* Mb = M + (size_t)b * 4096;
#pragma unroll
    for (int ct = 0; ct < 4; ++ct)
#pragma unroll
      for (int r = 0; r < 4; ++r)
        atomicAdd(&Mb[(ct * 16 + quad * 4 + r) * 64 + wq * 16 + lq], acc[ct][r]);
    return;
  }

  // ---------------- attention path (exact R6) ----------------
  const int q0 = x * 64;
  const int wb = wq * 32;
  const float* xub = xu + (size_t)b * 128 * HW;
  const float* xsb = xs + (size_t)b * 128 * HW;
  const u16* Kb = Knm + (size_t)b * HW * 64;
  const u16* Vb = Vcm + (size_t)b * 64 * HW;

  bh8 qb[4][2];
#pragma unroll
  for (int nt = 0; nt < 4; ++nt)
#pragma unroll
    for (int s = 0; s < 2; ++s)
#pragma unroll
      for (int j = 0; j < 8; ++j) {
        int ch = s * 32 + quad * 8 + j;
        qb[nt][s][j] =
            (short)f2bf(xub[(size_t)ch * HW + q0 + nt * 16 + lq] * 1.44269504f);
      }
  bh8 ones;
#pragma unroll
  for (int j = 0; j < 8; ++j) ones[j] = (short)0x3F80;

  f32x4 O[4][4];
#pragma unroll
  for (int ct = 0; ct < 4; ++ct)
#pragma unroll
    for (int nt = 0; nt < 4; ++nt) O[ct][nt] = (f32x4)(0.f);
  f32x4 Osum[4];
#pragma unroll
  for (int nt = 0; nt < 4; ++nt) Osum[nt] = (f32x4)(0.f);

  bh8 kfa[4], vfa[4], kfb[4], vfb[4];
  LOADKV(0, kfa, vfa);
  for (int kb = 0; kb < 32; kb += 2) {
    LOADKV(kb + 1, kfb, vfb);
    attn_step(kfa, vfa, qb, ones, O, Osum);
    if (kb + 2 < 32) LOADKV(kb + 2, kfa, vfa);
    attn_step(kfb, vfb, qb, ones, O, Osum);
  }

  // ---- epilogue: cross-wave reduce, normalize, shortcut, bf16 store ----
  float* Posc = (float*)SMEM;            // [4 waves][32 ch][68 q] = 34816 B
  float* Lred = (float*)(SMEM + 17408);  // 1024 B
  if (quad == 0) {
#pragma unroll
    for (int nt = 0; nt < 4; ++nt) Lred[(wq * 4 + nt) * 16 + lq] = Osum[nt][0];
  }

  const int q = t & 63, cg = t >> 6;
#pragma unroll
  for (int rh = 0; rh < 2; ++rh) {
    if (rh) __syncthreads();
#pragma unroll
    for (int c2 = 0; c2 < 2; ++c2)
#pragma unroll
      for (int nt = 0; nt < 4; ++nt)
#pragma unroll
        for (int r = 0; r < 4; ++r)
          Posc[(wq * 32 + c2 * 16 + quad * 4 + r) * 68 + nt * 16 + lq] =
              O[rh * 2 + c2][nt][r];
    __syncthreads();
    float li = 0.f;
#pragma unroll
    for (int w2 = 0; w2 < 4; ++w2) li += Lred[w2 * 64 + q];
    float inv = 1.f / li;
    u16 h[8];
#pragma unroll
    for (int i = 0; i < 8; ++i) {
      int chl = cg * 8 + i;
      float s = 0.f;
#pragma unroll
      for (int w2 = 0; w2 < 4; ++w2) s += Posc[(w2 * 32 + chl) * 68 + q];
      int ch = rh * 32 + chl;
      size_t g = (size_t)ch * HW + q0 + q;
      h[i] = f2bf(s * inv + xub[g] + xsb[g]);
    }
    u32 pk[4];
#pragma unroll
    for (int j = 0; j < 4; ++j) pk[j] = (u32)h[2 * j] | ((u32)h[2 * j + 1] << 16);
    u16* ob = xcat + ((size_t)b * HW + q0 + q) * 128 + rh * 32 + cg * 8;
    *(uint4*)ob = make_uint4(pk[0], pk[1], pk[2], pk[3]);
  }
}

// ---------------------------------------------------------------------------
// chan_apply with fused softmax; 1D grid 512, b = bid&7 (XCD pinning so
// V2t[b]/xcat[b] stay on the producer's XCD L2). block 256.
// ---------------------------------------------------------------------------
__global__ __launch_bounds__(256) void chan_apply(
    const u16* __restrict__ V2t, const float* __restrict__ M,
    const float* __restrict__ xu, const float* __restrict__ xs,
    u16* __restrict__ xcat) {
  __shared__ float Vsm[64][65];
  __shared__ float As[64][65];
  __shared__ float red1[4][64], red2[4][64];
  const int bid = blockIdx.x;
  const int b = bid & 7, n0 = (bid >> 3) * 64, t = threadIdx.x;
  const int lane = t & 63, dg = t >> 6;
  const u16* Vb = V2t + (size_t)b * 64 * HW;
  for (int s = 0; s < 16; ++s) {
    int c = s * 4 + dg;
    Vsm[lane][c] = bf2f(Vb[(size_t)c * HW + n0 + lane]);
  }
  for (int idx = t; idx < 4096; idx += 256) As[idx >> 6][idx & 63] = M[b * 4096 + idx];
  __syncthreads();
  float mx = -1e30f;
#pragma unroll
  for (int i = 0; i < 16; ++i) mx = fmaxf(mx, As[dg * 16 + i][lane]);
  red1[dg][lane] = mx;
  __syncthreads();
  mx = fmaxf(fmaxf(red1[0][lane], red1[1][lane]), fmaxf(red1[2][lane], red1[3][lane]));
  float se = 0.f;
#pragma unroll
  for (int i = 0; i < 16; ++i) {
    float e = __expf(As[dg * 16 + i][lane] - mx);
    As[dg * 16 + i][lane] = e;
    se += e;
  }
  red2[dg][lane] = se;
  __syncthreads();

  float acc[16];
#pragma unroll
  for (int i = 0; i < 16; ++i) acc[i] = 0.f;
  for (int c = 0; c < 64; ++c) {
    float v = Vsm[lane][c];
#pragma unroll
    for (int i = 0; i < 16; ++i) acc[i] = fmaf(v, As[c][dg * 16 + i], acc[i]);
  }
  const float* xub = xu + ((size_t)b * 128 + 64) * HW;
  const float* xsb = xs + ((size_t)b * 128 + 64) * HW;
  const int n = n0 + lane;
  u16 hv[16];
#pragma unroll
  for (int i = 0; i < 16; ++i) {
    int d = dg * 16 + i;
    float sm = red2[0][d] + red2[1][d] + red2[2][d] + red2[3][d];
    hv[i] = f2bf(acc[i] / sm + xub[(size_t)d * HW + n] + xsb[(size_t)d * HW + n]);
  }
  u32 pk[8];
#pragma unroll
  for (int j = 0; j < 8; ++j) pk[j] = (u32)hv[2 * j] | ((u32)hv[2 * j + 1] << 16);
  u16* ob = xcat + ((size_t)b * HW + n) * 128 + 64 + dg * 16;
  *(uint4*)(ob) = make_uint4(pk[0], pk[1], pk[2], pk[3]);
  *(uint4*)(ob + 8) = make_uint4(pk[4], pk[5], pk[6], pk[7]);
}

// ---------------------------------------------------------------------------
// Implicit-GEMM 3x3 conv (R6 version) with XCD pinning: 1D grid 256,
// b = bid&7 -> batch b's 32 blocks land on XCD b where xcat[b] is L2-warm.
// block 512.
// ---------------------------------------------------------------------------
__global__ __launch_bounds__(512) void conv_mfma(
    const u16* __restrict__ X, const u16* __restrict__ Wg,
    const float* __restrict__ shb, float* __restrict__ out) {
  __shared__ __align__(16) u16 In[4 * 66 * 136];
  __shared__ __align__(16) u16 Wt[2][128 * 136];
  const int bid = blockIdx.x;
  const int b = bid & 7, h0 = (bid >> 3) * 2;
  const int t = threadIdx.x;
  const int wq = t >> 6, lane = t & 63, lq = lane & 15, quad = lane >> 4;
  const int nb = (wq & 1) * 64;
  const int mb = (wq >> 1) * 2;
  const u16* Xb = X + (size_t)b * HW * 128;

  if (t < 128) {
    int ih = t >> 5, iwsel = (t >> 4) & 1, ck = t & 15;
    int iw = iwsel ? 65 : 0;
    *(uint4*)&In[(ih * 66 + iw) * 136 + ck * 8] = make_uint4(0, 0, 0, 0);
  }
  for (int ih = 0; ih < 4; ++ih) {
    int h = h0 - 1 + ih;
    bool ok = (h >= 0 && h < 64);
    const u16* src = Xb + (size_t)h * 64 * 128;
#pragma unroll
    for (int p = 0; p < 2; ++p) {
      int idx = p * 512 + t;
      int row = idx >> 4, ck = idx & 15;
      uint4 d = make_uint4(0, 0, 0, 0);
      if (ok) d = *(const uint4*)(src + (size_t)row * 128 + ck * 8);
      *(uint4*)&In[(ih * 66 + 1 + row) * 136 + ck * 8] = d;
    }
  }
  {
    const u16* src = Wg;
#pragma unroll
    for (int p = 0; p < 4; ++p) {
      int idx = p * 512 + t;
      int oc = idx >> 4, ck = idx & 15;
      uint4 d = *(const uint4*)(src + oc * 128 + ck * 8);
      *(uint4*)&Wt[0][oc * 136 + ck * 8] = d;
    }
  }
  __syncthreads();

  f32x4 acc[2][4];
#pragma unroll
  for (int mt = 0; mt < 2; ++mt)
#pragma unroll
    for (int nt = 0; nt < 4; ++nt) acc[mt][nt] = (f32x4)(0.f);

  for (int tap = 0; tap < 9; ++tap) {
    const int cur = tap & 1;
    if (tap < 8) {
      const u16* src = Wg + (size_t)(tap + 1) * 128 * 128;
#pragma unroll
      for (int p = 0; p < 4; ++p) {
        int idx = p * 512 + t;
        int oc = idx >> 4, ck = idx & 15;
        uint4 d = *(const uint4*)(src + oc * 128 + ck * 8);
        *(uint4*)&Wt[cur ^ 1][oc * 136 + ck * 8] = d;
      }
    }
    const int dh = tap / 3, dw = tap - 3 * dh;
    const u16* Wc = &Wt[cur][0];
#pragma unroll
    for (int c = 0; c < 4; ++c) {
      bh8 bf[4];
#pragma unroll
      for (int nt = 0; nt < 4; ++nt)
        bf[nt] = *(const bh8*)&Wc[(nb + nt * 16 + lq) * 136 + c * 32 + quad * 8];
#pragma unroll
      for (int mt = 0; mt < 2; ++mt) {
        int s = (mb + mt) * 16 + lq;
        int ih = (s >> 6) + dh, iw = (s & 63) + dw;
        bh8 af = *(const bh8*)&In[(ih * 66 + iw) * 136 + c * 32 + quad * 8];
#pragma unroll
        for (int nt = 0; nt < 4; ++nt)
          acc[mt][nt] = __builtin_amdgcn_mfma_f32_16x16x32_bf16(af, bf[nt], acc[mt][nt], 0, 0, 0);
      }
    }
    __syncthreads();
  }

  float shv[4];
#pragma unroll
  for (int nt = 0; nt < 4; ++nt) shv[nt] = shb[nb + nt * 16 + lq];
#pragma unroll
  for (int mt = 0; mt < 2; ++mt) {
    int mtile = mb + mt;
    int h = h0 + (mtile >> 2);
    int w0 = ((mtile & 3) * 16) + quad * 4;
#pragma unroll
    for (int nt = 0; nt < 4; ++nt) {
      int oc = nb + nt * 16 + lq;
      float4 v;
      v.x = fmaxf(acc[mt][nt][0] + shv[nt], 0.f);
      v.y = fmaxf(acc[mt][nt][1] + shv[nt], 0.f);
      v.z = fmaxf(acc[mt][nt][2] + shv[nt], 0.f);
      v.w = fmaxf(acc[mt][nt][3] + shv[nt], 0.f);
      *(float4*)&out[((size_t)b * 128 + oc) * HW + h * 64 + w0] = v;
    }
  }
}

// ---------------------------------------------------------------------------
extern "C" void kernel_launch(void* const* d_in, const int* in_sizes, int n_in,
                              void* d_out, int out_size, void* d_ws, size_t ws_size,
                              hipStream_t stream) {
  const float* x_up   = (const float*)d_in[0];
  const float* x_skip = (const float*)d_in[1];
  const float* kv1_w  = (const float*)d_in[2];
  const float* kv1_b  = (const float*)d_in[3];
  const float* kv2_w  = (const float*)d_in[4];
  const float* kv2_b  = (const float*)d_in[5];
  const float* conv_w = (const float*)d_in[6];
  const float* bn_g   = (const float*)d_in[7];
  const float* bn_b   = (const float*)d_in[8];
  const float* bn_m   = (const float*)d_in[9];
  const float* bn_v   = (const float*)d_in[10];
  float* out = (float*)d_out;

  char* ws = (char*)d_ws;
  const size_t XCATB_B = (size_t)8 * HW * 128 * 2;  // 8.39 MB bf16 n-major
  const size_t KV16_B  = (size_t)8 * 64 * HW * 2;   // 4.19 MB
  size_t off = 0;
  u16*   xcat = (u16*)(ws + off);   off += XCATB_B;
  u16*   K2t  = (u16*)(ws + off);   off += KV16_B;
  u16*   V2t  = (u16*)(ws + off);   off += KV16_B;
  u32*   Knm  = (u32*)(ws + off);   off += KV16_B;
  u16*   Vcm  = (u16*)(ws + off);   off += KV16_B;
  float* M    = (float*)(ws + off); off += (size_t)8 * 4096 * 4;
  u16*   Wg   = (u16*)(ws + off);   off += (size_t)9 * 128 * 128 * 2;
  float* shb  = (float*)(ws + off); off += 512;
  // total ~26 MB

  kv_proj<<<512, 256, 0, stream>>>(x_skip, kv1_w, kv1_b, kv2_w, kv2_b,
                                   Knm, Vcm, K2t, V2t,
                                   conv_w, bn_g, bn_b, bn_m, bn_v, Wg,
                                   shb, M);
  attn_gram<<<768, 256, 0, stream>>>(x_up, x_skip, (const u16*)Knm, Vcm,
                                     xcat, K2t, M);
  chan_apply<<<512, 256, 0, stream>>>(V2t, M, x_up, x_skip, xcat);
  conv_mfma<<<256, 512, 0, stream>>>(xcat, Wg, shb, out);
}